// Round 10
// baseline (200.490 us; speedup 1.0000x reference)
//
#include <hip/hip_runtime.h>
#include <hip/hip_fp16.h>
#include <stdint.h>

// VM-factorized voxel grid: N pts -> 48 feats (3 planes x 16ch) -> 27 outputs.
// Pipeline: memset coarse-hist(512) -> prep (planes/lines -> fp16 channel-last,
// basis -> MFMA B-frags, coarse hist) -> scan -> scatter (LDS rank, contiguous runs)
// -> eval: 2 lanes/point, fp16 gathers, fp16 packed interp, 3x mfma_f32_32x32x16_f16,
// direct coalesced stores from MFMA fragments (no LDS staging, no barrier).

constexpr int NPTS = 2097152;
constexpr int CCH  = 16;
constexpr int RES  = 320;
constexpr long long HW = (long long)RES * RES;   // 102400
constexpr int FD   = 27;
constexpr int BLK  = 256;
constexpr int NCELL = 512;                       // 8^3 coarse Morton cells
constexpr int PTS_PER_SORTBLK = 4096;            // 256 thr x 16 pts

constexpr int HIST_BLOCKS = NPTS / PTS_PER_SORTBLK;   // 512
constexpr int PLANE_BLOCKS = 1200;               // 3 * 400
constexpr int LINE_BLOCKS = 4;

// ---- workspace layout (bytes), all 16B-aligned ----
constexpr size_t WS_PLANEH = 0;                                   // 3*HW*16*2 = 9,830,400
constexpr size_t WS_LINEH  = WS_PLANEH + 3ull*HW*CCH*2;           // 30,720
constexpr size_t WS_BFRAG  = WS_LINEH + 3ull*RES*CCH*2;           // 3*64*8*2 = 3,072
constexpr size_t WS_CHIST  = WS_BFRAG + 3072;                     // 2,048
constexpr size_t WS_CURSOR = WS_CHIST + (size_t)NCELL*4;          // 2,048
constexpr size_t WS_SORTED = WS_CURSOR + (size_t)NCELL*4;         // N*16
constexpr size_t WS_NEED   = WS_SORTED + (size_t)NPTS*16;         // ~43.4 MB

typedef _Float16 half8 __attribute__((ext_vector_type(8)));
typedef float f32x16 __attribute__((ext_vector_type(16)));

// ---------------- helpers ----------------
__device__ __forceinline__ unsigned spread3(unsigned v) {
    return (v & 1u) | ((v & 2u) << 2) | ((v & 4u) << 4);
}
__device__ __forceinline__ int cell_key8(float px, float py, float pz) {
    int cx = min(max((int)((px + 1.f) * 4.f), 0), 7);
    int cy = min(max((int)((py + 1.f) * 4.f), 0), 7);
    int cz = min(max((int)((pz + 1.f) * 4.f), 0), 7);
    return (int)(spread3((unsigned)cx) | (spread3((unsigned)cy) << 1) | (spread3((unsigned)cz) << 2));
}

// ---------------- prep: coarse hist + planes/lines fp16 + basis B-frags ----------------
__global__ __launch_bounds__(BLK) void prep_kernel(
    const float* __restrict__ pts,
    const float* __restrict__ pxy, const float* __restrict__ pxz, const float* __restrict__ pyz,
    const float* __restrict__ vx, const float* __restrict__ vy, const float* __restrict__ vz,
    const float* __restrict__ basis,
    __half* __restrict__ planesH, __half* __restrict__ linesH, __half* __restrict__ bfragH,
    unsigned* __restrict__ chist) {
    __shared__ unsigned lh[NCELL];
    const int bid = blockIdx.x;
    const int tid = threadIdx.x;
    if (bid < HIST_BLOCKS) {                // coarse histogram, 4096 pts/block
        lh[tid] = 0u; lh[tid + 256] = 0u;
        __syncthreads();
        const float4* p4 = ((const float4*)pts) + (size_t)bid * 3072;
        #pragma unroll
        for (int g = 0; g < 4; ++g) {
            const float4 a = p4[tid*12 + g*3 + 0];
            const float4 b = p4[tid*12 + g*3 + 1];
            const float4 c = p4[tid*12 + g*3 + 2];
            atomicAdd(&lh[cell_key8(a.x, a.y, a.z)], 1u);
            atomicAdd(&lh[cell_key8(a.w, b.x, b.y)], 1u);
            atomicAdd(&lh[cell_key8(b.z, b.w, c.x)], 1u);
            atomicAdd(&lh[cell_key8(c.y, c.z, c.w)], 1u);
        }
        __syncthreads();
        if (lh[tid])       atomicAdd(&chist[tid],       lh[tid]);
        if (lh[tid + 256]) atomicAdd(&chist[tid + 256], lh[tid + 256]);
    } else if (bid < HIST_BLOCKS + PLANE_BLOCKS) {   // planes -> fp16 channel-last
        const int pb = bid - HIST_BLOCKS;
        const int plane = pb / 400;
        const int texel = (pb % 400) * BLK + tid;
        const float* src = (plane == 0) ? pxy : (plane == 1 ? pxz : pyz);
        union { ushort u[16]; uint4 q[2]; } pk;
        #pragma unroll
        for (int c = 0; c < CCH; ++c)
            pk.u[c] = __half_as_ushort(__float2half(src[(size_t)c * HW + texel]));
        uint4* dst = (uint4*)(planesH + ((size_t)plane * HW + texel) * CCH);
        dst[0] = pk.q[0]; dst[1] = pk.q[1];
    } else if (bid < HIST_BLOCKS + PLANE_BLOCKS + LINE_BLOCKS) {  // lines
        const int idx = (bid - HIST_BLOCKS - PLANE_BLOCKS) * BLK + tid;
        if (idx >= 3 * RES) return;
        const int axis = idx / RES, t = idx % RES;
        const float* src = (axis == 0) ? vx : (axis == 1 ? vy : vz);
        union { ushort u[16]; uint4 q[2]; } pk;
        #pragma unroll
        for (int c = 0; c < CCH; ++c)
            pk.u[c] = __half_as_ushort(__float2half(src[c * RES + t]));
        uint4* dst = (uint4*)(linesH + ((size_t)axis * RES + t) * CCH);
        dst[0] = pk.q[0]; dst[1] = pk.q[1];
    } else {   // basis (48,27) -> MFMA B-frag fp16: bfrag[r][lane][j] = basis[r*16+(l>>5)*8+j][l&31]
        if (tid < 192) {
            const int r = tid >> 6, l = tid & 63;
            const int col = l & 31, kb = l >> 5;
            __half* dst = bfragH + tid * 8;
            #pragma unroll
            for (int j = 0; j < 8; ++j) {
                float v = (col < FD) ? basis[(r * 16 + kb * 8 + j) * FD + col] : 0.f;
                dst[j] = __float2half(v);
            }
        }
    }
}

// ---------------- scan: exclusive scan of 512 coarse-cell counts -> cursor ----------------
__global__ __launch_bounds__(NCELL) void scan_kernel(const unsigned* __restrict__ chist,
                                                     unsigned* __restrict__ cursor) {
    __shared__ unsigned l[NCELL];
    const int t = threadIdx.x;
    const unsigned v = chist[t];
    l[t] = v;
    __syncthreads();
    for (int o = 1; o < NCELL; o <<= 1) {
        unsigned u = (t >= o) ? l[t - o] : 0u;
        __syncthreads();
        l[t] += u;
        __syncthreads();
    }
    cursor[t] = l[t] - v;   // exclusive
}

// ---------------- scatter: LDS rank + 1 global atomic per (block,cell) ----------------
__global__ __launch_bounds__(BLK) void scatter_kernel(const float* __restrict__ pts,
                                                      unsigned* __restrict__ cursor,
                                                      float4* __restrict__ sorted) {
    __shared__ unsigned lh[NCELL];
    __shared__ unsigned lb[NCELL];
    const int bid = blockIdx.x;
    const int tid = threadIdx.x;
    lh[tid] = 0u; lh[tid + 256] = 0u;
    __syncthreads();
    const float4* p4 = ((const float4*)pts) + (size_t)bid * 3072;
    unsigned kr[16];   // (key<<16) | rank
    #pragma unroll
    for (int g = 0; g < 4; ++g) {
        const float4 a = p4[tid*12 + g*3 + 0];
        const float4 b = p4[tid*12 + g*3 + 1];
        const float4 c = p4[tid*12 + g*3 + 2];
        int k; unsigned r;
        k = cell_key8(a.x, a.y, a.z); r = atomicAdd(&lh[k], 1u); kr[g*4+0] = ((unsigned)k << 16) | r;
        k = cell_key8(a.w, b.x, b.y); r = atomicAdd(&lh[k], 1u); kr[g*4+1] = ((unsigned)k << 16) | r;
        k = cell_key8(b.z, b.w, c.x); r = atomicAdd(&lh[k], 1u); kr[g*4+2] = ((unsigned)k << 16) | r;
        k = cell_key8(c.y, c.z, c.w); r = atomicAdd(&lh[k], 1u); kr[g*4+3] = ((unsigned)k << 16) | r;
    }
    __syncthreads();
    lb[tid]       = atomicAdd(&cursor[tid],       lh[tid]);
    lb[tid + 256] = atomicAdd(&cursor[tid + 256], lh[tid + 256]);
    __syncthreads();
    const int ibase = bid * PTS_PER_SORTBLK + tid * 16;
    #pragma unroll
    for (int g = 0; g < 4; ++g) {
        const float4 a = p4[tid*12 + g*3 + 0];
        const float4 b = p4[tid*12 + g*3 + 1];
        const float4 c = p4[tid*12 + g*3 + 2];
        unsigned e;
        e = kr[g*4+0]; sorted[lb[e >> 16] + (e & 0xffffu)] = make_float4(a.x, a.y, a.z, __int_as_float(ibase + g*4 + 0));
        e = kr[g*4+1]; sorted[lb[e >> 16] + (e & 0xffffu)] = make_float4(a.w, b.x, b.y, __int_as_float(ibase + g*4 + 1));
        e = kr[g*4+2]; sorted[lb[e >> 16] + (e & 0xffffu)] = make_float4(b.z, b.w, c.x, __int_as_float(ibase + g*4 + 2));
        e = kr[g*4+3]; sorted[lb[e >> 16] + (e & 0xffffu)] = make_float4(c.y, c.z, c.w, __int_as_float(ibase + g*4 + 3));
    }
}

// ---------------- eval ----------------
// Per lane: interpolate 8 channels (one plane-half, h = lane>>5) of its point
// (lane&31) in packed fp16, emit as MFMA A-fragment slot.
__device__ __forceinline__ half8 interp8h(const uint4* __restrict__ P, const uint4* __restrict__ L,
                                          int t00, int t01, int t10, int t11, int l0, int l1,
                                          float wc, float wr, float lw, int h) {
    union U { uint4 u; __half2 h2[4]; half8 v; };
    U c00, c01, c10, c11, la, lb, res;
    c00.u = P[2*t00 + h]; c01.u = P[2*t01 + h];
    c10.u = P[2*t10 + h]; c11.u = P[2*t11 + h];
    la.u  = L[2*l0 + h];  lb.u  = L[2*l1 + h];
    const float w00 = (1.f - wc) * (1.f - wr), w01 = wc * (1.f - wr);
    const float w10 = (1.f - wc) * wr,         w11 = wc * wr;
    const __half2 w00h = __float2half2_rn(w00), w01h = __float2half2_rn(w01);
    const __half2 w10h = __float2half2_rn(w10), w11h = __float2half2_rn(w11);
    const __half2 lwh  = __float2half2_rn(lw),  mlwh = __float2half2_rn(1.f - lw);
    #pragma unroll
    for (int q = 0; q < 4; ++q) {
        __half2 s = __hmul2(c00.h2[q], w00h);
        s = __hfma2(c01.h2[q], w01h, s);
        s = __hfma2(c10.h2[q], w10h, s);
        s = __hfma2(c11.h2[q], w11h, s);
        __half2 l = __hmul2(la.h2[q], mlwh);
        l = __hfma2(lb.h2[q], lwh, l);
        res.h2[q] = __hmul2(s, l);
    }
    return res.v;
}

__global__ __launch_bounds__(BLK) void eval_kernel(
    const float4* __restrict__ sorted,
    const __half* __restrict__ planesH,
    const __half* __restrict__ linesH,
    const __half* __restrict__ bfragH,
    float* __restrict__ out) {
    __shared__ int s_oi[BLK];                    // 1 KB, only LDS use
    constexpr int NBLK = NPTS / BLK;            // 8192
    constexpr int CHUNK = NBLK / 8;             // 1024
    const int bid = blockIdx.x;
    const int tid = threadIdx.x;
    const int swz = (bid & 7) * CHUNK + (bid >> 3);   // contiguous sorted range per XCD
    const int wid = tid >> 6, lane = tid & 63;
    const int pcol = lane & 31, kb = lane >> 5;

    // B fragments (basis rows 0-15 / 16-31 / 32-47), held in registers
    union BU { uint4 u; half8 h; } b0u, b1u, b2u;
    const uint4* bf = (const uint4*)bfragH;
    b0u.u = bf[lane]; b1u.u = bf[64 + lane]; b2u.u = bf[128 + lane];

    const uint4* Pxy = (const uint4*)planesH;
    const uint4* Pxz = (const uint4*)(planesH + (size_t)HW * CCH);
    const uint4* Pyz = (const uint4*)(planesH + (size_t)2 * HW * CCH);
    const uint4* Lx = (const uint4*)linesH;
    const uint4* Ly = (const uint4*)(linesH + (size_t)RES * CCH);
    const uint4* Lz = (const uint4*)(linesH + (size_t)2 * RES * CCH);

    const int blockbase = swz * BLK;
    #pragma unroll
    for (int t = 0; t < 2; ++t) {
        const int tbase = wid * 64 + t * 32;          // tile base within block
        const float4 pt = sorted[blockbase + tbase + pcol];
        const float px = pt.x, py = pt.y, pz = pt.z;
        if (kb == 0) s_oi[tbase + pcol] = __float_as_int(pt.w);

        const float scl = 0.5f * (RES - 1);
        const float fx = (px + 1.f) * scl, fy = (py + 1.f) * scl, fz = (pz + 1.f) * scl;
        const float xf = floorf(fx), yf = floorf(fy), zf = floorf(fz);
        const float wx = fx - xf, wy = fy - yf, wz = fz - zf;
        int x0 = min(max((int)xf, 0), RES - 1);
        int y0 = min(max((int)yf, 0), RES - 1);
        int z0 = min(max((int)zf, 0), RES - 1);
        const int x1 = min(x0 + 1, RES - 1);
        const int y1 = min(y0 + 1, RES - 1);
        const int z1 = min(z0 + 1, RES - 1);

        f32x16 acc;
        #pragma unroll
        for (int r = 0; r < 16; ++r) acc[r] = 0.f;

        half8 a0 = interp8h(Pxy, Lz, y0*RES+x0, y0*RES+x1, y1*RES+x0, y1*RES+x1, z0, z1, wx, wy, wz, kb);
        acc = __builtin_amdgcn_mfma_f32_32x32x16_f16(a0, b0u.h, acc, 0, 0, 0);
        half8 a1 = interp8h(Pxz, Ly, z0*RES+x0, z0*RES+x1, z1*RES+x0, z1*RES+x1, y0, y1, wx, wz, wy, kb);
        acc = __builtin_amdgcn_mfma_f32_32x32x16_f16(a1, b1u.h, acc, 0, 0, 0);
        half8 a2 = interp8h(Pyz, Lx, z0*RES+y0, z0*RES+y1, z1*RES+y0, z1*RES+y1, x0, x1, wy, wz, wx, kb);
        acc = __builtin_amdgcn_mfma_f32_32x32x16_f16(a2, b2u.h, acc, 0, 0, 0);

        // Direct coalesced stores from the D fragment:
        // D: col(=feature) = lane&31, row(=point) = (r&3) + 8*(r>>2) + 4*kb.
        // Per r, lanes 0-26 write point row(r,0)'s 27 features, lanes 32-58 point row(r,1)'s.
        if (pcol < FD) {
            #pragma unroll
            for (int r = 0; r < 16; ++r) {
                const int row = (r & 3) + 8 * (r >> 2) + 4 * kb;
                const int o = s_oi[tbase + row];
                out[(size_t)o * FD + pcol] = acc[r];
            }
        }
    }
}

// ---------------- fallback (no workspace) ----------------
__device__ __forceinline__ float bilerp(const float* __restrict__ p,
                                        int o00, int o01, int o10, int o11,
                                        float wc, float wr) {
    float v00 = p[o00], v01 = p[o01], v10 = p[o10], v11 = p[o11];
    float top = v00 + wc * (v01 - v00);
    float bot = v10 + wc * (v11 - v10);
    return top + wr * (bot - top);
}

__global__ __launch_bounds__(BLK) void vm_eval_fallback(
    const float* __restrict__ pts,
    const float* __restrict__ pxy, const float* __restrict__ pyz, const float* __restrict__ pxz,
    const float* __restrict__ vx, const float* __restrict__ vy, const float* __restrict__ vz,
    const float* __restrict__ basis, float* __restrict__ out) {
    const long long i = (long long)blockIdx.x * BLK + threadIdx.x;
    const float px = pts[i*3], py = pts[i*3+1], pz = pts[i*3+2];
    const float scl = 0.5f * (RES - 1);
    const float fx = (px + 1.f) * scl, fy = (py + 1.f) * scl, fz = (pz + 1.f) * scl;
    const float xf = floorf(fx), yf = floorf(fy), zf = floorf(fz);
    const float wx = fx - xf, wy = fy - yf, wz = fz - zf;
    int x0 = min(max((int)xf, 0), RES - 1);
    int y0 = min(max((int)yf, 0), RES - 1);
    int z0 = min(max((int)zf, 0), RES - 1);
    const int x1 = min(x0+1, RES-1), y1 = min(y0+1, RES-1), z1 = min(z0+1, RES-1);
    float acc[FD];
    #pragma unroll
    for (int f = 0; f < FD; ++f) acc[f] = 0.f;
    #pragma unroll 4
    for (int c = 0; c < CCH; ++c) {
        const float* a = pxy + c * HW;
        const float* b = pxz + c * HW;
        const float* d = pyz + c * HW;
        float lz = vz[c*RES+z0]; lz += wz * (vz[c*RES+z1] - lz);
        float ly = vy[c*RES+y0]; ly += wy * (vy[c*RES+y1] - ly);
        float lx = vx[c*RES+x0]; lx += wx * (vx[c*RES+x1] - lx);
        const float fa = bilerp(a, y0*RES+x0, y0*RES+x1, y1*RES+x0, y1*RES+x1, wx, wy) * lz;
        const float fb = bilerp(b, z0*RES+x0, z0*RES+x1, z1*RES+x0, z1*RES+x1, wx, wz) * ly;
        const float fc = bilerp(d, z0*RES+y0, z0*RES+y1, z1*RES+y0, z1*RES+y1, wy, wz) * lx;
        #pragma unroll
        for (int f = 0; f < FD; ++f)
            acc[f] += fa * basis[c*FD+f] + fb * basis[(CCH+c)*FD+f] + fc * basis[(2*CCH+c)*FD+f];
    }
    float* op = out + i * FD;
    #pragma unroll
    for (int f = 0; f < FD; ++f) op[f] = acc[f];
}

extern "C" void kernel_launch(void* const* d_in, const int* in_sizes, int n_in,
                              void* d_out, int out_size, void* d_ws, size_t ws_size,
                              hipStream_t stream) {
    const float* pts   = (const float*)d_in[0];
    const float* pxy   = (const float*)d_in[1];
    const float* pyz   = (const float*)d_in[2];
    const float* pxz   = (const float*)d_in[3];
    const float* vx    = (const float*)d_in[4];
    const float* vy    = (const float*)d_in[5];
    const float* vz    = (const float*)d_in[6];
    const float* basis = (const float*)d_in[7];
    float* out = (float*)d_out;

    if (ws_size < WS_NEED) {
        vm_eval_fallback<<<NPTS / BLK, BLK, 0, stream>>>(pts, pxy, pyz, pxz, vx, vy, vz, basis, out);
        return;
    }

    uint8_t* w = (uint8_t*)d_ws;
    __half*   planesH = (__half*)(w + WS_PLANEH);
    __half*   linesH  = (__half*)(w + WS_LINEH);
    __half*   bfragH  = (__half*)(w + WS_BFRAG);
    unsigned* chist   = (unsigned*)(w + WS_CHIST);
    unsigned* cursor  = (unsigned*)(w + WS_CURSOR);
    float4*   sorted  = (float4*)(w + WS_SORTED);

    hipMemsetAsync(chist, 0, (size_t)NCELL * 4, stream);
    prep_kernel<<<HIST_BLOCKS + PLANE_BLOCKS + LINE_BLOCKS + 1, BLK, 0, stream>>>(
        pts, pxy, pxz, pyz, vx, vy, vz, basis, planesH, linesH, bfragH, chist);
    scan_kernel<<<1, NCELL, 0, stream>>>(chist, cursor);
    scatter_kernel<<<HIST_BLOCKS, BLK, 0, stream>>>(pts, cursor, sorted);
    eval_kernel<<<NPTS / BLK, BLK, 0, stream>>>(sorted, planesH, linesH, bfragH, out);
}